// Round 4
// baseline (702.545 us; speedup 1.0000x reference)
//
#include <hip/hip_runtime.h>

#define BATCH 32
#define TIME  512
#define INF   512
#define HIDF  1024

#define RR 8   // bt rows per thread
#define CC 4   // h columns per lane (stride 64)

// ---------------------------------------------------------------------------
// Phase 1: hidden[bt][h] = (sum_k x[bt,k]*W[h,k]) + bias[h], bit-exact vs the
// XLA canonical order: per output ONE fp32 accumulator, fused FMA, k strictly
// ascending 0..511, then ONE fp32 rounding for +bias.  (Verified round 3.)
//
// Register blocking R=8 x C=4: 32 independent chains/thread, 128 FMAs per
// 12 float4 loads -> ~91% FMA issue density. x addresses are wave-uniform.
// ---------------------------------------------------------------------------
__global__ __launch_bounds__(256)
void snn_gemm_seqfma(const float* __restrict__ x, const float* __restrict__ W,
                     const float* __restrict__ bias, float* __restrict__ hidden) {
    const int lane = threadIdx.x & 63;
    const int wv   = __builtin_amdgcn_readfirstlane((int)(threadIdx.x >> 6)); // wave 0..3
    const int h0   = blockIdx.x * 256 + lane;      // cols: h0 + 64*c
    const int bt0  = blockIdx.y * 32 + wv * RR;    // this wave's 8 bt rows

    float acc[RR][CC];
    #pragma unroll
    for (int t = 0; t < RR; ++t)
        #pragma unroll
        for (int c = 0; c < CC; ++c) acc[t][c] = 0.0f;

    const float4* wp[CC];
    #pragma unroll
    for (int c = 0; c < CC; ++c)
        wp[c] = (const float4*)(W + (size_t)(h0 + 64 * c) * INF);
    const float4* xp[RR];
    #pragma unroll
    for (int t = 0; t < RR; ++t)
        xp[t] = (const float4*)(x + (size_t)(bt0 + t) * INF);

    for (int kq = 0; kq < INF / 4; ++kq) {         // one float4 (4 k) per step
        float4 wv4[CC];
        #pragma unroll
        for (int c = 0; c < CC; ++c) wv4[c] = wp[c][kq];
        float4 xv4[RR];
        #pragma unroll
        for (int t = 0; t < RR; ++t) xv4[t] = xp[t][kq];   // wave-uniform

        // k strictly ascending within the quad; 32 independent chains
        #pragma unroll
        for (int t = 0; t < RR; ++t)
            #pragma unroll
            for (int c = 0; c < CC; ++c)
                acc[t][c] = __fmaf_rn(xv4[t].x, wv4[c].x, acc[t][c]);
        #pragma unroll
        for (int t = 0; t < RR; ++t)
            #pragma unroll
            for (int c = 0; c < CC; ++c)
                acc[t][c] = __fmaf_rn(xv4[t].y, wv4[c].y, acc[t][c]);
        #pragma unroll
        for (int t = 0; t < RR; ++t)
            #pragma unroll
            for (int c = 0; c < CC; ++c)
                acc[t][c] = __fmaf_rn(xv4[t].z, wv4[c].z, acc[t][c]);
        #pragma unroll
        for (int t = 0; t < RR; ++t)
            #pragma unroll
            for (int c = 0; c < CC; ++c)
                acc[t][c] = __fmaf_rn(xv4[t].w, wv4[c].w, acc[t][c]);
    }

    float bv[CC];
    #pragma unroll
    for (int c = 0; c < CC; ++c) bv[c] = bias[h0 + 64 * c];
    #pragma unroll
    for (int t = 0; t < RR; ++t)
        #pragma unroll
        for (int c = 0; c < CC; ++c)
            hidden[(size_t)(bt0 + t) * HIDF + h0 + 64 * c] = __fadd_rn(acc[t][c], bv[c]);
}

// ---------------------------------------------------------------------------
// Phase 2: in-place LIF scan over t per (b,h) column, fp32:
//   mem = fl32(0.5*mem + h_t)  (0.5*mem exact -> single rounding per step);
//   spk = mem > 1.0f; hard reset to 0.
// ---------------------------------------------------------------------------
__global__ __launch_bounds__(256)
void snn_scan_np(float* __restrict__ io) {
    const int n = blockIdx.x * 256 + threadIdx.x;   // 0..32767
    const int b = n >> 10;
    const int h = n & 1023;
    float* p = io + (size_t)b * TIME * HIDF + h;

    float mem = 0.0f;
    for (int tb = 0; tb < TIME / 32; ++tb) {
        float hv[32];
        #pragma unroll
        for (int u = 0; u < 32; ++u) hv[u] = p[(size_t)(tb * 32 + u) * HIDF];
        float sp[32];
        #pragma unroll
        for (int u = 0; u < 32; ++u) {
            mem = __fadd_rn(__fmul_rn(0.5f, mem), hv[u]);
            bool s = mem > 1.0f;
            sp[u] = s ? 1.0f : 0.0f;
            if (s) mem = 0.0f;
        }
        #pragma unroll
        for (int u = 0; u < 32; ++u) p[(size_t)(tb * 32 + u) * HIDF] = sp[u];
    }
}

extern "C" void kernel_launch(void* const* d_in, const int* in_sizes, int n_in,
                              void* d_out, int out_size, void* d_ws, size_t ws_size,
                              hipStream_t stream) {
    const float* x    = (const float*)d_in[0];   // [32, 512, 512]
    const float* W    = (const float*)d_in[1];   // [1024, 512]
    const float* bias = (const float*)d_in[2];   // [1024]
    float* out = (float*)d_out;                  // [32, 512, 1024]

    dim3 g1(HIDF / (64 * CC), (BATCH * TIME) / 32);   // (4, 512)
    snn_gemm_seqfma<<<g1, 256, 0, stream>>>(x, W, bias, out);

    snn_scan_np<<<(BATCH * HIDF) / 256, 256, 0, stream>>>(out);
}

// Round 5
// 623.903 us; speedup vs baseline: 1.1260x; 1.1260x over previous
//
#include <hip/hip_runtime.h>

#define BATCH 32
#define TIME  512
#define INF   512
#define HIDF  1024

#define RR   8   // bt rows per wave
#define CCOL 8   // h columns per lane (stride 64)
#define KC   8   // k per chunk (2 float4 per col)

// ---------------------------------------------------------------------------
// Phase 1: hidden[bt][h] = (sum_k x[bt,k]*W[h,k]) + bias[h], bit-exact vs the
// XLA canonical order (verified round 3): per output ONE fp32 accumulator,
// fused FMA, k strictly ascending 0..511, then ONE fp32 rounding for +bias.
//
// Anti-latency structure (R4 post-mortem: compiler sank loads, VGPR=36,
// VALUBusy 19%):
//   - x tile (32 rows x 512 k = 64 KB) persistent in LDS, staged once,
//     NO barriers in the K-loop; main-loop x reads are ds_read broadcasts.
//   - W staged 16 float4 per chunk into registers, with sched_barrier(0)
//     fencing the stage from the FMA body so loads batch under one vmcnt.
//   - C=8 x R=8 register tile: 512 FMAs per chunk per wave.
// ---------------------------------------------------------------------------
__global__ __launch_bounds__(256, 2)
void snn_gemm_seqfma(const float* __restrict__ x, const float* __restrict__ W,
                     const float* __restrict__ bias, float* __restrict__ hidden) {
    __shared__ __align__(16) float xs[32 * INF];   // 64 KB

    const int tid  = threadIdx.x;
    const int lane = tid & 63;
    const int wv   = __builtin_amdgcn_readfirstlane(tid >> 6);  // wave 0..3
    const int hb   = blockIdx.x * 512 + lane;       // cols: hb + 64*c
    const int bt0  = blockIdx.y * 32;               // block's 32 bt rows

    // ---- one-time coalesced stage of x[bt0:bt0+32][:] into LDS ----
    {
        const float4* gx = (const float4*)(x + (size_t)bt0 * INF);
        float4* lx = (float4*)xs;
        #pragma unroll
        for (int j = 0; j < 16; ++j)
            lx[j * 256 + tid] = gx[j * 256 + tid];
    }
    __syncthreads();

    float acc[RR][CCOL];
    #pragma unroll
    for (int r = 0; r < RR; ++r)
        #pragma unroll
        for (int c = 0; c < CCOL; ++c) acc[r][c] = 0.0f;

    const float4* wp[CCOL];
    #pragma unroll
    for (int c = 0; c < CCOL; ++c)
        wp[c] = (const float4*)(W + (size_t)(hb + 64 * c) * INF);

    for (int kc = 0; kc < INF / KC; ++kc) {        // 64 chunks of 8 k
        // ---- batched W stage: 16 independent float4 loads ----
        float4 wb[CCOL][2];
        #pragma unroll
        for (int c = 0; c < CCOL; ++c) {
            wb[c][0] = wp[c][kc * 2 + 0];
            wb[c][1] = wp[c][kc * 2 + 1];
        }
        __builtin_amdgcn_sched_barrier(0);         // loads stay batched above

        #pragma unroll
        for (int r = 0; r < RR; ++r) {
            const float4* xr = (const float4*)(xs + (wv * RR + r) * INF) + kc * 2;
            float4 x0 = xr[0];
            float4 x1 = xr[1];
            // k strictly ascending within the chunk for every (r,c) chain
            #pragma unroll
            for (int c = 0; c < CCOL; ++c) acc[r][c] = __fmaf_rn(x0.x, wb[c][0].x, acc[r][c]);
            #pragma unroll
            for (int c = 0; c < CCOL; ++c) acc[r][c] = __fmaf_rn(x0.y, wb[c][0].y, acc[r][c]);
            #pragma unroll
            for (int c = 0; c < CCOL; ++c) acc[r][c] = __fmaf_rn(x0.z, wb[c][0].z, acc[r][c]);
            #pragma unroll
            for (int c = 0; c < CCOL; ++c) acc[r][c] = __fmaf_rn(x0.w, wb[c][0].w, acc[r][c]);
            #pragma unroll
            for (int c = 0; c < CCOL; ++c) acc[r][c] = __fmaf_rn(x1.x, wb[c][1].x, acc[r][c]);
            #pragma unroll
            for (int c = 0; c < CCOL; ++c) acc[r][c] = __fmaf_rn(x1.y, wb[c][1].y, acc[r][c]);
            #pragma unroll
            for (int c = 0; c < CCOL; ++c) acc[r][c] = __fmaf_rn(x1.z, wb[c][1].z, acc[r][c]);
            #pragma unroll
            for (int c = 0; c < CCOL; ++c) acc[r][c] = __fmaf_rn(x1.w, wb[c][1].w, acc[r][c]);
        }
    }

    float bv[CCOL];
    #pragma unroll
    for (int c = 0; c < CCOL; ++c) bv[c] = bias[hb + 64 * c];
    #pragma unroll
    for (int r = 0; r < RR; ++r)
        #pragma unroll
        for (int c = 0; c < CCOL; ++c)
            hidden[(size_t)(bt0 + wv * RR + r) * HIDF + hb + 64 * c] =
                __fadd_rn(acc[r][c], bv[c]);
}

// ---------------------------------------------------------------------------
// Phase 2: in-place LIF scan over t per (b,h) column, fp32:
//   mem = fl32(0.5*mem + h_t); spk = mem > 1.0f; hard reset to 0.
// ---------------------------------------------------------------------------
__global__ __launch_bounds__(256)
void snn_scan_np(float* __restrict__ io) {
    const int n = blockIdx.x * 256 + threadIdx.x;   // 0..32767
    const int b = n >> 10;
    const int h = n & 1023;
    float* p = io + (size_t)b * TIME * HIDF + h;

    float mem = 0.0f;
    for (int tb = 0; tb < TIME / 32; ++tb) {
        float hv[32];
        #pragma unroll
        for (int u = 0; u < 32; ++u) hv[u] = p[(size_t)(tb * 32 + u) * HIDF];
        float sp[32];
        #pragma unroll
        for (int u = 0; u < 32; ++u) {
            mem = __fadd_rn(__fmul_rn(0.5f, mem), hv[u]);
            bool s = mem > 1.0f;
            sp[u] = s ? 1.0f : 0.0f;
            if (s) mem = 0.0f;
        }
        #pragma unroll
        for (int u = 0; u < 32; ++u) p[(size_t)(tb * 32 + u) * HIDF] = sp[u];
    }
}

extern "C" void kernel_launch(void* const* d_in, const int* in_sizes, int n_in,
                              void* d_out, int out_size, void* d_ws, size_t ws_size,
                              hipStream_t stream) {
    const float* x    = (const float*)d_in[0];   // [32, 512, 512]
    const float* W    = (const float*)d_in[1];   // [1024, 512]
    const float* bias = (const float*)d_in[2];   // [1024]
    float* out = (float*)d_out;                  // [32, 512, 1024]

    dim3 g1(HIDF / 512, (BATCH * TIME) / 32);    // (2, 512)
    snn_gemm_seqfma<<<g1, 256, 0, stream>>>(x, W, bias, out);

    snn_scan_np<<<(BATCH * HIDF) / 256, 256, 0, stream>>>(out);
}

// Round 6
// 516.759 us; speedup vs baseline: 1.3595x; 1.2073x over previous
//
#include <hip/hip_runtime.h>

#define BATCH 32
#define TIME  512
#define INF   512
#define HIDF  1024

#define MBT  128          // block tile: bt rows
#define NBH  128          // block tile: h cols
#define KCH  16           // k per chunk
#define NCH  (INF / KCH)  // 32 chunks
#define LSTR 132          // LDS row stride (floats): 128 + 4 pad

// ---------------------------------------------------------------------------
// Phase 1: hidden[bt][h] = (sum_k x[bt,k]*W[h,k]) + bias[h], bit-exact vs the
// XLA canonical order (verified R3): per output ONE fp32 accumulator, fused
// FMA, k strictly ascending, then ONE fp32 rounding for +bias.
//
// R5 post-mortem: W was a 64-way per-instruction gather (lanes 2 KB apart)
// -> ~262k L1 transactions/block -> VMEM-transaction-bound at VALUBusy 26%.
// Now BOTH operands stage global->LDS with full-line coalescing (4-lane
// clusters = one 64B line), transposed LDS tiles:
//   xs[k][bt], ws[k][h], stride 132 (staging writes 2-way=free; x-frag reads
//   conflict-free; w-frag reads 4-way=1.58x, LDS pipe non-critical).
// Thread tile 8x8; per k-step: 4 ds_read_b128 + 64 FMA. Register prefetch of
// chunk kc+1 issues before chunk kc's 1024 FMAs (sched_barrier pins it).
// ---------------------------------------------------------------------------
__global__ __launch_bounds__(256, 3)
void snn_gemm_seqfma(const float* __restrict__ x, const float* __restrict__ W,
                     const float* __restrict__ bias, float* __restrict__ hidden) {
    __shared__ __align__(16) float xs[KCH * LSTR];   // 8448 B
    __shared__ __align__(16) float ws[KCH * LSTR];   // 8448 B

    const int tid = threadIdx.x;
    const int tx  = tid & 15;        // col group: h = h0 + tx*8 + c
    const int ty  = tid >> 4;        // row group: bt = bt0 + ty*8 + r
    const int bt0 = blockIdx.y * MBT;
    const int h0  = blockIdx.x * NBH;

    // staging quads: q0 = tid, q1 = tid+256; row = q>>2 (0..127), kq = q&3
    const int q0 = tid,      r0 = q0 >> 2, kq0 = q0 & 3;
    const int q1 = tid + 256, r1 = q1 >> 2, kq1 = q1 & 3;
    const float4* xg0 = (const float4*)(x + (size_t)(bt0 + r0) * INF) + kq0;
    const float4* xg1 = (const float4*)(x + (size_t)(bt0 + r1) * INF) + kq1;
    const float4* wg0 = (const float4*)(W + (size_t)(h0 + r0) * INF) + kq0;
    const float4* wg1 = (const float4*)(W + (size_t)(h0 + r1) * INF) + kq1;

    float acc[8][8];
    #pragma unroll
    for (int r = 0; r < 8; ++r)
        #pragma unroll
        for (int c = 0; c < 8; ++c) acc[r][c] = 0.0f;

    float4 px0 = xg0[0], px1 = xg1[0], pw0 = wg0[0], pw1 = wg1[0];

    for (int kc = 0; kc < NCH; ++kc) {
        // ---- write prefetched chunk into LDS, transposed ----
        xs[(4*kq0+0)*LSTR + r0] = px0.x;
        xs[(4*kq0+1)*LSTR + r0] = px0.y;
        xs[(4*kq0+2)*LSTR + r0] = px0.z;
        xs[(4*kq0+3)*LSTR + r0] = px0.w;
        xs[(4*kq1+0)*LSTR + r1] = px1.x;
        xs[(4*kq1+1)*LSTR + r1] = px1.y;
        xs[(4*kq1+2)*LSTR + r1] = px1.z;
        xs[(4*kq1+3)*LSTR + r1] = px1.w;
        ws[(4*kq0+0)*LSTR + r0] = pw0.x;
        ws[(4*kq0+1)*LSTR + r0] = pw0.y;
        ws[(4*kq0+2)*LSTR + r0] = pw0.z;
        ws[(4*kq0+3)*LSTR + r0] = pw0.w;
        ws[(4*kq1+0)*LSTR + r1] = pw1.x;
        ws[(4*kq1+1)*LSTR + r1] = pw1.y;
        ws[(4*kq1+2)*LSTR + r1] = pw1.z;
        ws[(4*kq1+3)*LSTR + r1] = pw1.w;
        __syncthreads();

        // ---- issue next chunk's global loads; latency hidden by 1024 FMAs ----
        if (kc + 1 < NCH) {
            px0 = xg0[(kc + 1) * 4];
            px1 = xg1[(kc + 1) * 4];
            pw0 = wg0[(kc + 1) * 4];
            pw1 = wg1[(kc + 1) * 4];
        }
        __builtin_amdgcn_sched_barrier(0);   // loads may not sink into compute

        // ---- compute: per k, 4 ds_read_b128 + 64 FMA ----
        #pragma unroll
        for (int k = 0; k < KCH; ++k) {
            float4 xa = *(const float4*)(xs + k * LSTR + ty * 8);
            float4 xb = *(const float4*)(xs + k * LSTR + ty * 8 + 4);
            float4 wa = *(const float4*)(ws + k * LSTR + tx * 8);
            float4 wb = *(const float4*)(ws + k * LSTR + tx * 8 + 4);
            float xf[8] = {xa.x, xa.y, xa.z, xa.w, xb.x, xb.y, xb.z, xb.w};
            float wf[8] = {wa.x, wa.y, wa.z, wa.w, wb.x, wb.y, wb.z, wb.w};
            #pragma unroll
            for (int r = 0; r < 8; ++r)
                #pragma unroll
                for (int c = 0; c < 8; ++c)
                    acc[r][c] = __fmaf_rn(xf[r], wf[c], acc[r][c]);
        }
        __syncthreads();
    }

    // ---- epilogue: one fp32 rounding for bias, coalesced-ish stores ----
    float bv[8];
    #pragma unroll
    for (int c = 0; c < 8; ++c) bv[c] = bias[h0 + tx * 8 + c];
    #pragma unroll
    for (int r = 0; r < 8; ++r) {
        float* orow = hidden + (size_t)(bt0 + ty * 8 + r) * HIDF + h0 + tx * 8;
        float4 o0, o1;
        o0.x = __fadd_rn(acc[r][0], bv[0]);
        o0.y = __fadd_rn(acc[r][1], bv[1]);
        o0.z = __fadd_rn(acc[r][2], bv[2]);
        o0.w = __fadd_rn(acc[r][3], bv[3]);
        o1.x = __fadd_rn(acc[r][4], bv[4]);
        o1.y = __fadd_rn(acc[r][5], bv[5]);
        o1.z = __fadd_rn(acc[r][6], bv[6]);
        o1.w = __fadd_rn(acc[r][7], bv[7]);
        ((float4*)orow)[0] = o0;
        ((float4*)orow)[1] = o1;
    }
}

// ---------------------------------------------------------------------------
// Phase 2: in-place LIF scan over t per (b,h) column, fp32:
//   mem = fl32(0.5*mem + h_t); spk = mem > 1.0f; hard reset to 0.
// ---------------------------------------------------------------------------
__global__ __launch_bounds__(256)
void snn_scan_np(float* __restrict__ io) {
    const int n = blockIdx.x * 256 + threadIdx.x;   // 0..32767
    const int b = n >> 10;
    const int h = n & 1023;
    float* p = io + (size_t)b * TIME * HIDF + h;

    float mem = 0.0f;
    for (int tb = 0; tb < TIME / 32; ++tb) {
        float hv[32];
        #pragma unroll
        for (int u = 0; u < 32; ++u) hv[u] = p[(size_t)(tb * 32 + u) * HIDF];
        float sp[32];
        #pragma unroll
        for (int u = 0; u < 32; ++u) {
            mem = __fadd_rn(__fmul_rn(0.5f, mem), hv[u]);
            bool s = mem > 1.0f;
            sp[u] = s ? 1.0f : 0.0f;
            if (s) mem = 0.0f;
        }
        #pragma unroll
        for (int u = 0; u < 32; ++u) p[(size_t)(tb * 32 + u) * HIDF] = sp[u];
    }
}

extern "C" void kernel_launch(void* const* d_in, const int* in_sizes, int n_in,
                              void* d_out, int out_size, void* d_ws, size_t ws_size,
                              hipStream_t stream) {
    const float* x    = (const float*)d_in[0];   // [32, 512, 512]
    const float* W    = (const float*)d_in[1];   // [1024, 512]
    const float* bias = (const float*)d_in[2];   // [1024]
    float* out = (float*)d_out;                  // [32, 512, 1024]

    dim3 g1(HIDF / NBH, (BATCH * TIME) / MBT);   // (8, 128) = 1024 blocks
    snn_gemm_seqfma<<<g1, 256, 0, stream>>>(x, W, bias, out);

    snn_scan_np<<<(BATCH * HIDF) / 256, 256, 0, stream>>>(out);
}

// Round 7
// 350.420 us; speedup vs baseline: 2.0049x; 1.4747x over previous
//
#include <hip/hip_runtime.h>

#define BATCH 32
#define TIME  512
#define INF   512
#define HIDF  1024

#define MBT  128          // block tile: bt rows
#define NBH  128          // block tile: h cols
#define KCH  16           // k per chunk
#define NCH  (INF / KCH)  // 32 chunks
#define TILEF (MBT * KCH) // 2048 floats = 8 KB per buffer

// async global->LDS DMA, 16 B per lane, dst = wave-uniform base + lane*16
#define GLD16(g, l) __builtin_amdgcn_global_load_lds(                      \
    (const __attribute__((address_space(1))) void*)(g),                    \
    (__attribute__((address_space(3))) void*)(l), 16, 0, 0)

// ---------------------------------------------------------------------------
// Phase 1: hidden[bt][h] = (sum_k x[bt,k]*W[h,k]) + bias[h], bit-exact vs the
// XLA canonical order (verified R3): ONE fp32 accumulator per output, fused
// FMA, k strictly ascending, ONE fp32 rounding for +bias.
//
// R6 post-mortem: register prefetch spilled to scratch (VGPR=84, ~740 MB HBM
// scratch traffic). Now staging is global_load_lds double-buffering: no VGPR
// round-trip, nothing spillable. LDS tiles row-major [row][16k] (DMA is
// lane-contiguous, no padding possible); XOR swizzle quad^=(row>>3)&3 makes
// x-frag b128 reads conflict-free, W-frag reads 4-way (LDS pipe non-critical:
// ~290 cyc/group vs 512 VALU cyc/group).
// ---------------------------------------------------------------------------
__global__ __launch_bounds__(256, 3)
void snn_gemm_seqfma(const float* __restrict__ x, const float* __restrict__ W,
                     const float* __restrict__ bias, float* __restrict__ hidden) {
    __shared__ __align__(16) float xs[2 * TILEF];   // 16 KB
    __shared__ __align__(16) float ws[2 * TILEF];   // 16 KB

    const int tid = threadIdx.x;
    const int l   = tid & 63;
    const int wv  = __builtin_amdgcn_readfirstlane(tid >> 6);  // wave 0..3
    const int tx  = tid & 15;        // col group: h = h0 + tx*8 + c
    const int ty  = tid >> 4;        // row group: bt = bt0 + ty*8 + r
    const int bt0 = blockIdx.y * MBT;
    const int h0  = blockIdx.x * NBH;

    // ---- DMA source setup: each wave stages rows 32wv..32wv+31 of x and W.
    // Instr A: rows 32wv+(l>>2); instr B: +16. Lane loads quad (l&3)^key(row).
    const int rl   = l >> 2;
    const int qs   = l & 3;
    const int rowA = 32 * wv + rl;
    const int rowB = rowA + 16;
    const int qA   = qs ^ ((rowA >> 3) & 3);
    const int qB   = qs ^ ((rowB >> 3) & 3);
    const float* xgA = x + (size_t)(bt0 + rowA) * INF + qA * 4;
    const float* xgB = x + (size_t)(bt0 + rowB) * INF + qB * 4;
    const float* wgA = W + (size_t)(h0 + rowA) * INF + qA * 4;
    const float* wgB = W + (size_t)(h0 + rowB) * INF + qB * 4;
    const int dOffA = (32 * wv) * KCH;        // wave-uniform LDS float offset
    const int dOffB = dOffA + 16 * KCH;

    // ---- prologue: stage chunk 0 into buffer 0 ----
    GLD16(xgA, xs + dOffA);
    GLD16(xgB, xs + dOffB);
    GLD16(wgA, ws + dOffA);
    GLD16(wgB, ws + dOffB);

    float acc[8][8];
    #pragma unroll
    for (int r = 0; r < 8; ++r)
        #pragma unroll
        for (int c = 0; c < 8; ++c) acc[r][c] = 0.0f;

    __syncthreads();   // drains vmcnt -> chunk 0 resident

    for (int kc = 0; kc < NCH; ++kc) {
        const int p  = kc & 1;
        const int np = p ^ 1;

        // ---- issue next chunk's DMAs into the other buffer (async) ----
        if (kc + 1 < NCH) {
            const int so = (kc + 1) * KCH;    // float offset within a row
            float* xd = xs + np * TILEF;
            float* wd = ws + np * TILEF;
            GLD16(xgA + so, xd + dOffA);
            GLD16(xgB + so, xd + dOffB);
            GLD16(wgA + so, wd + dOffA);
            GLD16(wgB + so, wd + dOffB);
        }

        // ---- compute on current buffer: 4 groups of 4 k ----
        const float* xb = xs + p * TILEF;
        const float* wb = ws + p * TILEF;
        #pragma unroll
        for (int g = 0; g < 4; ++g) {
            const int gx_ = (g ^ (ty & 3)) * 4;   // swizzled quad for x rows
            const int gw_ = (g ^ (tx & 3)) * 4;   // swizzled quad for W rows
            float4 xf[8], wf[8];
            #pragma unroll
            for (int r = 0; r < 8; ++r)
                xf[r] = *(const float4*)(xb + (ty * 8 + r) * KCH + gx_);
            #pragma unroll
            for (int c = 0; c < 8; ++c)
                wf[c] = *(const float4*)(wb + (tx * 8 + c) * KCH + gw_);
            // k strictly ascending within the group for every (r,c) chain
            #pragma unroll
            for (int r = 0; r < 8; ++r)
                #pragma unroll
                for (int c = 0; c < 8; ++c)
                    acc[r][c] = __fmaf_rn(xf[r].x, wf[c].x, acc[r][c]);
            #pragma unroll
            for (int r = 0; r < 8; ++r)
                #pragma unroll
                for (int c = 0; c < 8; ++c)
                    acc[r][c] = __fmaf_rn(xf[r].y, wf[c].y, acc[r][c]);
            #pragma unroll
            for (int r = 0; r < 8; ++r)
                #pragma unroll
                for (int c = 0; c < 8; ++c)
                    acc[r][c] = __fmaf_rn(xf[r].z, wf[c].z, acc[r][c]);
            #pragma unroll
            for (int r = 0; r < 8; ++r)
                #pragma unroll
                for (int c = 0; c < 8; ++c)
                    acc[r][c] = __fmaf_rn(xf[r].w, wf[c].w, acc[r][c]);
        }
        __syncthreads();   // all waves done with buf p; buf np's DMAs drained
    }

    // ---- epilogue: one fp32 rounding for bias, float4 stores ----
    float bv[8];
    #pragma unroll
    for (int c = 0; c < 8; ++c) bv[c] = bias[h0 + tx * 8 + c];
    #pragma unroll
    for (int r = 0; r < 8; ++r) {
        float* orow = hidden + (size_t)(bt0 + ty * 8 + r) * HIDF + h0 + tx * 8;
        float4 o0, o1;
        o0.x = __fadd_rn(acc[r][0], bv[0]);
        o0.y = __fadd_rn(acc[r][1], bv[1]);
        o0.z = __fadd_rn(acc[r][2], bv[2]);
        o0.w = __fadd_rn(acc[r][3], bv[3]);
        o1.x = __fadd_rn(acc[r][4], bv[4]);
        o1.y = __fadd_rn(acc[r][5], bv[5]);
        o1.z = __fadd_rn(acc[r][6], bv[6]);
        o1.w = __fadd_rn(acc[r][7], bv[7]);
        ((float4*)orow)[0] = o0;
        ((float4*)orow)[1] = o1;
    }
}

// ---------------------------------------------------------------------------
// Phase 2: in-place LIF scan over t per (b,h) column, fp32:
//   mem = fl32(0.5*mem + h_t); spk = mem > 1.0f; hard reset to 0.
// ---------------------------------------------------------------------------
__global__ __launch_bounds__(256)
void snn_scan_np(float* __restrict__ io) {
    const int n = blockIdx.x * 256 + threadIdx.x;   // 0..32767
    const int b = n >> 10;
    const int h = n & 1023;
    float* p = io + (size_t)b * TIME * HIDF + h;

    float mem = 0.0f;
    for (int tb = 0; tb < TIME / 32; ++tb) {
        float hv[32];
        #pragma unroll
        for (int u = 0; u < 32; ++u) hv[u] = p[(size_t)(tb * 32 + u) * HIDF];
        float sp[32];
        #pragma unroll
        for (int u = 0; u < 32; ++u) {
            mem = __fadd_rn(__fmul_rn(0.5f, mem), hv[u]);
            bool s = mem > 1.0f;
            sp[u] = s ? 1.0f : 0.0f;
            if (s) mem = 0.0f;
        }
        #pragma unroll
        for (int u = 0; u < 32; ++u) p[(size_t)(tb * 32 + u) * HIDF] = sp[u];
    }
}

extern "C" void kernel_launch(void* const* d_in, const int* in_sizes, int n_in,
                              void* d_out, int out_size, void* d_ws, size_t ws_size,
                              hipStream_t stream) {
    const float* x    = (const float*)d_in[0];   // [32, 512, 512]
    const float* W    = (const float*)d_in[1];   // [1024, 512]
    const float* bias = (const float*)d_in[2];   // [1024]
    float* out = (float*)d_out;                  // [32, 512, 1024]

    dim3 g1(HIDF / NBH, (BATCH * TIME) / MBT);   // (8, 128) = 1024 blocks
    snn_gemm_seqfma<<<g1, 256, 0, stream>>>(x, W, bias, out);

    snn_scan_np<<<(BATCH * HIDF) / 256, 256, 0, stream>>>(out);
}

// Round 8
// 327.870 us; speedup vs baseline: 2.1428x; 1.0688x over previous
//
#include <hip/hip_runtime.h>

#define BATCH 32
#define TIME  512
#define INF   512
#define HIDF  1024

#define MBT  128          // block tile: bt rows
#define NBH  128          // block tile: h cols
#define KCH  16           // k per chunk
#define NCH  (INF / KCH)  // 32 chunks
#define TILEF (MBT * KCH) // 2048 floats = 8 KB per buffer

// async global->LDS DMA, 16 B per lane, dst = wave-uniform base + lane*16
#define GLD16(g, l) __builtin_amdgcn_global_load_lds(                      \
    (const __attribute__((address_space(1))) void*)(g),                    \
    (__attribute__((address_space(3))) void*)(l), 16, 0, 0)

// ---------------------------------------------------------------------------
// Phase 1: hidden[bt][h] = (sum_k x[bt,k]*W[h,k]) + bias[h], bit-exact vs the
// XLA canonical order (verified R3): ONE fp32 accumulator per output, fused
// FMA, k strictly ascending, ONE fp32 rounding for +bias.
//
// R7 post-mortem: W-frag reads were 4-way bank-conflicted (5.0e7 conflict
// cycles; LDS pipe ~205 us/CU > 109 us VALU floor). Fix: wave = 64x64
// sub-tile (2x2 wave grid), lane = 8x8 grid within it. Both frag reads now
// have 8 distinct addresses (8-lane broadcast); per-row quad-XOR makes them
// 2-way max = free. LDS pipe ~82 us/CU < VALU 109 us -> VALU-bound.
// ---------------------------------------------------------------------------
__global__ __launch_bounds__(256, 3)
void snn_gemm_seqfma(const float* __restrict__ x, const float* __restrict__ W,
                     const float* __restrict__ bias, float* __restrict__ hidden) {
    __shared__ __align__(16) float xs[2 * TILEF];   // 16 KB
    __shared__ __align__(16) float ws[2 * TILEF];   // 16 KB

    const int tid = threadIdx.x;
    const int l   = tid & 63;
    const int wv  = __builtin_amdgcn_readfirstlane(tid >> 6);  // wave 0..3
    const int lx  = l & 7;           // h octet within wave sub-tile
    const int ly  = (l >> 3) & 7;    // bt octet within wave sub-tile
    const int bt0 = blockIdx.y * MBT;
    const int h0  = blockIdx.x * NBH;
    // wave sub-tile origin inside the 128x128 block tile
    const int wbt = 64 * (wv >> 1);  // bt offset: 0 or 64
    const int wh  = 64 * (wv & 1);   // h  offset: 0 or 64

    // ---- DMA staging: wave wv stages rows 32wv..32wv+31 of x and W ----
    const int rl   = l >> 2;
    const int qs   = l & 3;
    const int rowA = 32 * wv + rl;
    const int rowB = rowA + 16;
    const int qA   = qs ^ ((rowA >> 3) & 3);
    const int qB   = qs ^ ((rowB >> 3) & 3);
    const float* xgA = x + (size_t)(bt0 + rowA) * INF + qA * 4;
    const float* xgB = x + (size_t)(bt0 + rowB) * INF + qB * 4;
    const float* wgA = W + (size_t)(h0 + rowA) * INF + qA * 4;
    const float* wgB = W + (size_t)(h0 + rowB) * INF + qB * 4;
    const int dOffA = (32 * wv) * KCH;        // wave-uniform LDS float offset
    const int dOffB = dOffA + 16 * KCH;

    // ---- prologue: stage chunk 0 into buffer 0 ----
    GLD16(xgA, xs + dOffA);
    GLD16(xgB, xs + dOffB);
    GLD16(wgA, ws + dOffA);
    GLD16(wgB, ws + dOffB);

    float acc[8][8];
    #pragma unroll
    for (int r = 0; r < 8; ++r)
        #pragma unroll
        for (int c = 0; c < 8; ++c) acc[r][c] = 0.0f;

    __syncthreads();   // drains vmcnt -> chunk 0 resident

    for (int kc = 0; kc < NCH; ++kc) {
        const int p  = kc & 1;
        const int np = p ^ 1;

        // ---- issue next chunk's DMAs into the other buffer (async) ----
        if (kc + 1 < NCH) {
            const int so = (kc + 1) * KCH;    // float offset within a row
            float* xd = xs + np * TILEF;
            float* wd = ws + np * TILEF;
            GLD16(xgA + so, xd + dOffA);
            GLD16(xgB + so, xd + dOffB);
            GLD16(wgA + so, wd + dOffA);
            GLD16(wgB + so, wd + dOffB);
        }

        // ---- compute on current buffer: 4 groups of 4 k, g ascending ----
        const float* xb = xs + p * TILEF;
        const float* wb = ws + p * TILEF;
        #pragma unroll
        for (int g = 0; g < 4; ++g) {
            const int gx_ = (g ^ (ly & 3)) * 4;   // quad position for x rows
            const int gw_ = (g ^ (lx & 3)) * 4;   // quad position for W rows
            float4 xf[8], wf[8];
            #pragma unroll
            for (int r = 0; r < 8; ++r)
                xf[r] = *(const float4*)(xb + (wbt + ly * 8 + r) * KCH + gx_);
            #pragma unroll
            for (int c = 0; c < 8; ++c)
                wf[c] = *(const float4*)(wb + (wh + lx * 8 + c) * KCH + gw_);
            // k strictly ascending within the group for every (r,c) chain
            #pragma unroll
            for (int r = 0; r < 8; ++r)
                #pragma unroll
                for (int c = 0; c < 8; ++c)
                    acc[r][c] = __fmaf_rn(xf[r].x, wf[c].x, acc[r][c]);
            #pragma unroll
            for (int r = 0; r < 8; ++r)
                #pragma unroll
                for (int c = 0; c < 8; ++c)
                    acc[r][c] = __fmaf_rn(xf[r].y, wf[c].y, acc[r][c]);
            #pragma unroll
            for (int r = 0; r < 8; ++r)
                #pragma unroll
                for (int c = 0; c < 8; ++c)
                    acc[r][c] = __fmaf_rn(xf[r].z, wf[c].z, acc[r][c]);
            #pragma unroll
            for (int r = 0; r < 8; ++r)
                #pragma unroll
                for (int c = 0; c < 8; ++c)
                    acc[r][c] = __fmaf_rn(xf[r].w, wf[c].w, acc[r][c]);
        }
        __syncthreads();   // all waves done with buf p; buf np's DMAs drained
    }

    // ---- epilogue: one fp32 rounding for bias, float4 stores ----
    float bv[8];
    #pragma unroll
    for (int c = 0; c < 8; ++c) bv[c] = bias[h0 + wh + lx * 8 + c];
    #pragma unroll
    for (int r = 0; r < 8; ++r) {
        float* orow = hidden + (size_t)(bt0 + wbt + ly * 8 + r) * HIDF
                             + h0 + wh + lx * 8;
        float4 o0, o1;
        o0.x = __fadd_rn(acc[r][0], bv[0]);
        o0.y = __fadd_rn(acc[r][1], bv[1]);
        o0.z = __fadd_rn(acc[r][2], bv[2]);
        o0.w = __fadd_rn(acc[r][3], bv[3]);
        o1.x = __fadd_rn(acc[r][4], bv[4]);
        o1.y = __fadd_rn(acc[r][5], bv[5]);
        o1.z = __fadd_rn(acc[r][6], bv[6]);
        o1.w = __fadd_rn(acc[r][7], bv[7]);
        ((float4*)orow)[0] = o0;
        ((float4*)orow)[1] = o1;
    }
}

// ---------------------------------------------------------------------------
// Phase 2: in-place LIF scan over t per (b,h) column, fp32:
//   mem = fl32(0.5*mem + h_t); spk = mem > 1.0f; hard reset to 0.
// Burst 64 t per round-trip: fewer exposed latency passes at 2 waves/CU.
// ---------------------------------------------------------------------------
__global__ __launch_bounds__(256)
void snn_scan_np(float* __restrict__ io) {
    const int n = blockIdx.x * 256 + threadIdx.x;   // 0..32767
    const int b = n >> 10;
    const int h = n & 1023;
    float* p = io + (size_t)b * TIME * HIDF + h;

    float mem = 0.0f;
    for (int tb = 0; tb < TIME / 64; ++tb) {
        float hv[64];
        #pragma unroll
        for (int u = 0; u < 64; ++u) hv[u] = p[(size_t)(tb * 64 + u) * HIDF];
        float sp[64];
        #pragma unroll
        for (int u = 0; u < 64; ++u) {
            mem = __fadd_rn(__fmul_rn(0.5f, mem), hv[u]);
            bool s = mem > 1.0f;
            sp[u] = s ? 1.0f : 0.0f;
            if (s) mem = 0.0f;
        }
        #pragma unroll
        for (int u = 0; u < 64; ++u) p[(size_t)(tb * 64 + u) * HIDF] = sp[u];
    }
}

extern "C" void kernel_launch(void* const* d_in, const int* in_sizes, int n_in,
                              void* d_out, int out_size, void* d_ws, size_t ws_size,
                              hipStream_t stream) {
    const float* x    = (const float*)d_in[0];   // [32, 512, 512]
    const float* W    = (const float*)d_in[1];   // [1024, 512]
    const float* bias = (const float*)d_in[2];   // [1024]
    float* out = (float*)d_out;                  // [32, 512, 1024]

    dim3 g1(HIDF / NBH, (BATCH * TIME) / MBT);   // (8, 128) = 1024 blocks
    snn_gemm_seqfma<<<g1, 256, 0, stream>>>(x, W, bias, out);

    snn_scan_np<<<(BATCH * HIDF) / 256, 256, 0, stream>>>(out);
}